// Round 5
// baseline (514.096 us; speedup 1.0000x reference)
//
#include <hip/hip_runtime.h>
#include <hip/hip_bf16.h>
#include <stdint.h>

#define D_MODEL 1024
#define NHEAD   16
#define HDIM    64
#define SEQ     2048
#define BH      64   // 4 batches * 16 heads

typedef short bf16x8 __attribute__((ext_vector_type(8)));
typedef float f32x4  __attribute__((ext_vector_type(4)));

static __device__ __forceinline__ float bf2f(ushort u) {
    union { uint32_t i; float f; } v; v.i = ((uint32_t)u) << 16; return v.f;
}
static __device__ __forceinline__ ushort f2bf(float f) {
    __hip_bfloat16 h = __float2bfloat16(f);
    union { __hip_bfloat16 h; ushort u; } v; v.h = h; return v.u;
}
static __device__ __forceinline__ uint32_t pk2(float a, float b) {
    return (uint32_t)f2bf(a) | ((uint32_t)f2bf(b) << 16);
}
// Load 8 fp32, convert to bf16 (RNE), store 16B to LDS.
static __device__ __forceinline__ void cvt_store8(ushort* dst, const float* src) {
    float4 a = *(const float4*)src;
    float4 b = *(const float4*)(src + 4);
    uint4 o;
    o.x = pk2(a.x, a.y);
    o.y = pk2(a.z, a.w);
    o.z = pk2(b.x, b.y);
    o.w = pk2(b.z, b.w);
    *(uint4*)dst = o;
}

// ---------------------------------------------------------------------------
// GEMM1: qkv = X[8192,1024](f32) * Wqkv[3072,1024](f32)^T, bf16 MFMA compute.
// Scatter epilogue: q,k -> [bh][s][d] bf16 ; v -> transposed [bh][d][s] bf16.
// ---------------------------------------------------------------------------
__global__ __launch_bounds__(256)
void gemm_qkv(const float* __restrict__ X, const float* __restrict__ W,
              ushort* __restrict__ qb, ushort* __restrict__ kb,
              ushort* __restrict__ vt)
{
    __shared__ ushort As[128 * 72];
    __shared__ ushort Bs[128 * 72];
    const int K = 1024;
    const int m0 = blockIdx.y * 128;
    const int n0 = blockIdx.x * 128;
    const int t = threadIdx.x;
    const int lane = t & 63, wv = t >> 6;
    const int wm = (wv >> 1) * 64, wn = (wv & 1) * 64;
    const int l15 = lane & 15, quad = lane >> 4;

    f32x4 acc[4][4];
#pragma unroll
    for (int i = 0; i < 4; i++)
#pragma unroll
        for (int j = 0; j < 4; j++) acc[i][j] = (f32x4){0.f, 0.f, 0.f, 0.f};

    for (int k0 = 0; k0 < K; k0 += 64) {
        __syncthreads();
#pragma unroll
        for (int i = 0; i < 4; i++) {
            int slot = t + 256 * i;
            int r = slot >> 3, c = (slot & 7) * 8;
            cvt_store8(&As[r * 72 + c], &X[(size_t)(m0 + r) * K + k0 + c]);
            cvt_store8(&Bs[r * 72 + c], &W[(size_t)(n0 + r) * K + k0 + c]);
        }
        __syncthreads();
#pragma unroll
        for (int ks = 0; ks < 2; ks++) {
            bf16x8 af[4], bfr[4];
            const int kc = ks * 32 + quad * 8;
#pragma unroll
            for (int mi = 0; mi < 4; mi++)
                af[mi] = *(const bf16x8*)&As[(wm + mi * 16 + l15) * 72 + kc];
#pragma unroll
            for (int ni = 0; ni < 4; ni++)
                bfr[ni] = *(const bf16x8*)&Bs[(wn + ni * 16 + l15) * 72 + kc];
#pragma unroll
            for (int ni = 0; ni < 4; ni++)
#pragma unroll
                for (int mi = 0; mi < 4; mi++)
                    acc[mi][ni] = __builtin_amdgcn_mfma_f32_16x16x32_bf16(
                        af[mi], bfr[ni], acc[mi][ni], 0, 0, 0);
        }
    }

#pragma unroll
    for (int ni = 0; ni < 4; ni++) {
        const int e = n0 + wn + ni * 16 + l15;
        const int which = e >> 10;
        const int h = (e >> 6) & 15;
        const int d = e & 63;
#pragma unroll
        for (int mi = 0; mi < 4; mi++) {
            const int gm0 = m0 + wm + mi * 16 + quad * 4;
            const int b = gm0 >> 11;
            const int s0 = gm0 & 2047;
            const int bh = b * NHEAD + h;
            if (which == 2) {
                ushort4 pk;
                pk.x = f2bf(acc[mi][ni][0]); pk.y = f2bf(acc[mi][ni][1]);
                pk.z = f2bf(acc[mi][ni][2]); pk.w = f2bf(acc[mi][ni][3]);
                *(ushort4*)&vt[((size_t)bh * HDIM + d) * SEQ + s0] = pk;
            } else {
                ushort* dst = (which == 0) ? qb : kb;
#pragma unroll
                for (int r = 0; r < 4; r++)
                    dst[((size_t)bh * SEQ + s0 + r) * HDIM + d] = f2bf(acc[mi][ni][r]);
            }
        }
    }
}

// ---------------------------------------------------------------------------
// GEMM2: out(f32) = A[8192,1024](bf16) * Wout[1024,1024](f32)^T
// ---------------------------------------------------------------------------
__global__ __launch_bounds__(256)
void gemm_out(const ushort* __restrict__ A, const float* __restrict__ W,
              float* __restrict__ out)
{
    __shared__ ushort As[128 * 72];
    __shared__ ushort Bs[128 * 72];
    const int K = 1024;
    const int m0 = blockIdx.y * 128;
    const int n0 = blockIdx.x * 128;
    const int t = threadIdx.x;
    const int lane = t & 63, wv = t >> 6;
    const int wm = (wv >> 1) * 64, wn = (wv & 1) * 64;
    const int l15 = lane & 15, quad = lane >> 4;

    f32x4 acc[4][4];
#pragma unroll
    for (int i = 0; i < 4; i++)
#pragma unroll
        for (int j = 0; j < 4; j++) acc[i][j] = (f32x4){0.f, 0.f, 0.f, 0.f};

    for (int k0 = 0; k0 < K; k0 += 64) {
        __syncthreads();
#pragma unroll
        for (int i = 0; i < 4; i++) {
            int slot = t + 256 * i;
            int r = slot >> 3, c = (slot & 7) * 8;
            *(uint4*)&As[r * 72 + c] = *(const uint4*)&A[(size_t)(m0 + r) * K + k0 + c];
            cvt_store8(&Bs[r * 72 + c], &W[(size_t)(n0 + r) * K + k0 + c]);
        }
        __syncthreads();
#pragma unroll
        for (int ks = 0; ks < 2; ks++) {
            bf16x8 af[4], bfr[4];
            const int kc = ks * 32 + quad * 8;
#pragma unroll
            for (int mi = 0; mi < 4; mi++)
                af[mi] = *(const bf16x8*)&As[(wm + mi * 16 + l15) * 72 + kc];
#pragma unroll
            for (int ni = 0; ni < 4; ni++)
                bfr[ni] = *(const bf16x8*)&Bs[(wn + ni * 16 + l15) * 72 + kc];
#pragma unroll
            for (int ni = 0; ni < 4; ni++)
#pragma unroll
                for (int mi = 0; mi < 4; mi++)
                    acc[mi][ni] = __builtin_amdgcn_mfma_f32_16x16x32_bf16(
                        af[mi], bfr[ni], acc[mi][ni], 0, 0, 0);
        }
    }

#pragma unroll
    for (int ni = 0; ni < 4; ni++) {
        const int n = n0 + wn + ni * 16 + l15;
#pragma unroll
        for (int mi = 0; mi < 4; mi++) {
            const int gm0 = m0 + wm + mi * 16 + quad * 4;
#pragma unroll
            for (int r = 0; r < 4; r++)
                out[(size_t)(gm0 + r) * 1024 + n] = acc[mi][ni][r];
        }
    }
}

// ---------------------------------------------------------------------------
// RoPE in-place on bf16 q and k buffers, layout [bh][s][64]. One thread/pair.
// ---------------------------------------------------------------------------
__global__ __launch_bounds__(256)
void rope_k(ushort* __restrict__ qb, ushort* __restrict__ kb)
{
    const int idx = blockIdx.x * blockDim.x + threadIdx.x;   // BH*SEQ*32 total
    const int i  = idx & 31;
    const int s  = (idx >> 5) & 2047;
    const int bh = idx >> 16;
    ushort* buf = blockIdx.y ? kb : qb;
    const size_t off = ((size_t)bh * SEQ + s) * HDIM + 2 * i;
    uint32_t pair = *(uint32_t*)&buf[off];
    float x1 = bf2f((ushort)(pair & 0xffff));
    float x2 = bf2f((ushort)(pair >> 16));
    float freq = expf(-(float)i * (9.2103403719761836f / 32.0f));  // 10000^(-i/32)
    float ang = (float)s * freq;
    float sn, cs;
    sincosf(ang, &sn, &cs);
    float o1 = x1 * cs - x2 * sn;
    float o2 = x2 * cs + x1 * sn;
    uint32_t op = (uint32_t)f2bf(o1) | ((uint32_t)f2bf(o2) << 16);
    *(uint32_t*)&buf[off] = op;
}

// ---------------------------------------------------------------------------
// Flash attention, causal — S^T formulation, ZERO LDS / ZERO barriers.
// K-fragments and V^T-fragments are loaded directly from global (L1/L2-hot:
// per-head K/V = 512 KB, reused by all q-tiles). Occupancy is VGPR-bound only;
// waves run fully async — vmcnt stalls hidden by ~20 waves/CU.
// Each block processes TWO paired q-tiles (qtA, 31-qtA) -> uniform 33
// k-iterations per block, killing tail imbalance. Per-tile math identical to
// the verified round-4 S^T algebra.
// ---------------------------------------------------------------------------
__global__ __launch_bounds__(256)
void attn_k(const ushort* __restrict__ qb, const ushort* __restrict__ kb,
            const ushort* __restrict__ vt, ushort* __restrict__ ao)
{
    const int qtA = blockIdx.x;      // 0..15 ; phase 1 uses 31-qtA
    const int bh = blockIdx.y;       // 0..63
    const int t = threadIdx.x;
    const int lane = t & 63, wv = t >> 6;
    const int l15 = lane & 15, quad = lane >> 4;
    const int b = bh >> 4, h = bh & 15;

    // per-lane fragment base pointers
    const ushort* kbL = kb + ((size_t)bh * SEQ + l15) * HDIM + quad * 8;
    const ushort* vtL = vt + ((size_t)bh * HDIM + l15) * SEQ + quad * 8;

    const int qlo = (quad & 1) * 2;
    const bool hi = (quad >= 2);

    for (int ph = 0; ph < 2; ph++) {
        const int qt = ph ? (31 - qtA) : qtA;
        const int q0 = qt * 64;
        const int qg = q0 + wv * 16 + l15;   // this lane's q (global)

        // Q fragments (B-operand of S^T) straight from global
        const ushort* qaL = qb + ((size_t)bh * SEQ + qg) * HDIM + quad * 8;
        bf16x8 qa[2];
        qa[0] = *(const bf16x8*)(qaL);
        qa[1] = *(const bf16x8*)(qaL + 32);

        f32x4 accO[4];                // O^T: row d = mi*16+quad*4+r, col q = l15
#pragma unroll
        for (int i = 0; i < 4; i++) accO[i] = (f32x4){0.f, 0.f, 0.f, 0.f};
        float m = -30000.f, l = 0.f;

        for (int kt = 0; kt <= qt; kt++) {
            const int k0 = kt * 64;

            // S^T = K Q^T : st[mi] rows k = k0+mi*16+quad*4+r, col q = l15
            f32x4 st[4];
#pragma unroll
            for (int mi = 0; mi < 4; mi++) st[mi] = (f32x4){0.f, 0.f, 0.f, 0.f};
#pragma unroll
            for (int ks = 0; ks < 2; ks++) {
#pragma unroll
                for (int mi = 0; mi < 4; mi++) {
                    bf16x8 ka = *(const bf16x8*)(kbL + (size_t)(k0 + mi * 16) * HDIM + ks * 32);
                    st[mi] = __builtin_amdgcn_mfma_f32_16x16x32_bf16(ka, qa[ks], st[mi], 0, 0, 0);
                }
            }

            const bool diag = (kt == qt);
#pragma unroll
            for (int mi = 0; mi < 4; mi++) {
#pragma unroll
                for (int r = 0; r < 4; r++) {
                    float v = st[mi][r] * 0.125f;
                    if (diag) {
                        int kg = k0 + mi * 16 + quad * 4 + r;
                        if (kg > qg) v = -30000.f;
                    }
                    st[mi][r] = v;
                }
            }

            // online softmax: in-lane tree over 16 k values + xor16/xor32
            float mx = st[0][0];
#pragma unroll
            for (int mi = 0; mi < 4; mi++)
#pragma unroll
                for (int r = 0; r < 4; r++) mx = fmaxf(mx, st[mi][r]);
            mx = fmaxf(mx, __shfl_xor(mx, 16));
            mx = fmaxf(mx, __shfl_xor(mx, 32));
            const float mnew = fmaxf(m, mx);
            const float alpha = __expf(m - mnew);
            float ssum = 0.f;
#pragma unroll
            for (int mi = 0; mi < 4; mi++)
#pragma unroll
                for (int r = 0; r < 4; r++) {
                    float pv = __expf(st[mi][r] - mnew);
                    st[mi][r] = pv;
                    ssum += pv;
                }
            ssum += __shfl_xor(ssum, 16);
            ssum += __shfl_xor(ssum, 32);
            l = l * alpha + ssum;
            m = mnew;
#pragma unroll
            for (int mi = 0; mi < 4; mi++)
#pragma unroll
                for (int r = 0; r < 4; r++) accO[mi][r] *= alpha;

            // pack P to bf16 pairs: pr[mi][w] = (k = k0+mi*16+quad*4+2w, +1)
            uint32_t pr[4][2];
#pragma unroll
            for (int mi = 0; mi < 4; mi++) {
                pr[mi][0] = pk2(st[mi][0], st[mi][1]);
                pr[mi][1] = pk2(st[mi][2], st[mi][3]);
            }

            // redistribute P^T into B-operand frags + PV MFMA
            //   mi_src = ks2*2 + (quad>>1); quad_src = (quad&1)*2 + (w>>1); w_src = w&1
#pragma unroll
            for (int ks2 = 0; ks2 < 2; ks2++) {
                uint32_t pb[4];
#pragma unroll
                for (int w = 0; w < 4; w++) {
                    int srcLane = (qlo + (w >> 1)) * 16 + l15;
                    uint32_t va = __shfl(pr[ks2 * 2 + 0][w & 1], srcLane);
                    uint32_t vb = __shfl(pr[ks2 * 2 + 1][w & 1], srcLane);
                    pb[w] = hi ? vb : va;
                }
                bf16x8 pfrag;
                *(uint4*)&pfrag = *(uint4*)pb;
#pragma unroll
                for (int mi = 0; mi < 4; mi++) {
                    bf16x8 vfr = *(const bf16x8*)(vtL + (size_t)mi * 16 * SEQ + k0 + ks2 * 32);
                    accO[mi] = __builtin_amdgcn_mfma_f32_16x16x32_bf16(vfr, pfrag, accO[mi], 0, 0, 0);
                }
            }
        }

        // epilogue: O[q][d] = accO^T / l ; lane: q = qg, d = mi*16+quad*4+r
        const float rl = 1.0f / fmaxf(l, 1e-20f);
#pragma unroll
        for (int mi = 0; mi < 4; mi++) {
            uint2 o;
            o.x = pk2(accO[mi][0] * rl, accO[mi][1] * rl);
            o.y = pk2(accO[mi][2] * rl, accO[mi][3] * rl);
            *(uint2*)&ao[((size_t)(b * SEQ + qg)) * D_MODEL + h * HDIM + mi * 16 + quad * 4] = o;
        }
    }
}

// ---------------------------------------------------------------------------
extern "C" void kernel_launch(void* const* d_in, const int* in_sizes, int n_in,
                              void* d_out, int out_size, void* d_ws, size_t ws_size,
                              hipStream_t stream)
{
    (void)out_size; (void)ws_size;
    int ix = 0, iwq = 1, iwo = 2;
    for (int i = 0; i < n_in; i++) {
        if (in_sizes[i] == 4 * SEQ * D_MODEL)          ix  = i;  // 8388608
        else if (in_sizes[i] == 3 * D_MODEL * D_MODEL) iwq = i;  // 3145728
        else if (in_sizes[i] == D_MODEL * D_MODEL)     iwo = i;  // 1048576
    }
    const float* X    = (const float*)d_in[ix];
    const float* Wqkv = (const float*)d_in[iwq];
    const float* Wout = (const float*)d_in[iwo];
    float* out = (float*)d_out;

    char* ws = (char*)d_ws;
    const size_t SZ = (size_t)BH * SEQ * HDIM * sizeof(ushort);  // 16.78 MB
    ushort* qb = (ushort*)(ws);
    ushort* kb = (ushort*)(ws + SZ);
    ushort* vt = (ushort*)(ws + 2 * SZ);
    ushort* ao = (ushort*)(ws + 3 * SZ);   // total ws use: 67.1 MB

    gemm_qkv<<<dim3(24, 64), 256, 0, stream>>>(X, Wqkv, qb, kb, vt);
    rope_k<<<dim3((BH * SEQ * 32) / 256, 2), 256, 0, stream>>>(qb, kb);
    attn_k<<<dim3(16, 64), 256, 0, stream>>>(qb, kb, vt, ao);
    gemm_out<<<dim3(8, 64), 256, 0, stream>>>(ao, Wout, out);
}